// Round 13
// baseline (14251.871 us; speedup 1.0000x reference)
//
#include <hip/hip_runtime.h>
#include <stdint.h>

#define N_STEPS 2000
#define DT_F 0.01f

typedef float f32x2 __attribute__((ext_vector_type(2)));
typedef float f32x4 __attribute__((ext_vector_type(4)));

// tanh(x) = 1 - 2/(exp2(2x*log2e)+1): mul, exp2, add, rcp, fma = 5 VALU.
__device__ __forceinline__ float fast_tanh(float x) {
    float e = __builtin_amdgcn_exp2f(x * 2.8853900817779268f);  // e^{2x}
    float r = __builtin_amdgcn_rcpf(e + 1.0f);
    return fmaf(-2.0f, r, 1.0f);
}

__device__ __forceinline__ float bperm(float v, int addr) {
    return __builtin_bit_cast(float, __builtin_amdgcn_ds_bpermute(
               addr, __builtin_bit_cast(int, v)));
}

__device__ __forceinline__ f32x2 lo2(f32x4 v) { return __builtin_shufflevector(v, v, 0, 1); }
__device__ __forceinline__ f32x2 hi2(f32x4 v) { return __builtin_shufflevector(v, v, 2, 3); }

// Split-half reduction (cross-lane ops ~8cyc on gfx950 made the DPP+readlane
// tree the single biggest per-eval cost: 14 ops = 112 cyc). This form uses
// 8 ds_bpermute (DS crossbar, off the VALU pipe) + 8 adds + 1 cndmask:
// result kq = k0 in lanes<32 / k1 in lanes>=32, kr = the swap. All consumers
// work lane-locally in this split layout.
__device__ __forceinline__ void kreduce(float p0, float p1, bool half0,
                                        int a1, int a2, int a4, int a8,
                                        int a16, int a32,
                                        float& kq, float& kr) {
    float f0 = p0 + bperm(p0, a32);   // fold halves: lane i: p0_i + p0_{i^32}
    float f1 = p1 + bperm(p1, a32);
    float q  = half0 ? f0 : f1;       // lanes<32: p0-partials; >=32: p1-partials
    q += bperm(q, a1);
    q += bperm(q, a2);
    q += bperm(q, a4);
    q += bperm(q, a8);
    q += bperm(q, a16);               // lanes<32: k0 ; lanes>=32: k1
    kq = q;
    kr = bperm(q, a32);               // the complementary half
}

__global__ __attribute__((amdgpu_flat_work_group_size(256, 256),
                          amdgpu_waves_per_eu(2, 2)))
void node_rk4_kernel(
    const float* __restrict__ y0_in,
    const float* __restrict__ W1, const float* __restrict__ B1,
    const float* __restrict__ W2, const float* __restrict__ B2,
    const float* __restrict__ W3, const float* __restrict__ B3,
    float* __restrict__ out, int batch)
{
    __shared__ __align__(16) float sW2T[64 * 66];   // W2^T, stride 66 (bank-spread)
    __shared__ __align__(16) float hl_all[4][2][64];

    const int tid  = threadIdx.x;
    const int lane = tid & 63;
    const int wib  = tid >> 6;                   // wave-in-block 0..3
    const int w    = blockIdx.x * 4 + wib;       // wave id
    const int bA   = 2 * w;                      // two samples per wave
    const int bB   = 2 * w + 1;

    // One-time stage of W2^T into LDS.
    for (int idx = tid; idx < 64 * 64; idx += 256) {
        sW2T[(idx & 63) * 66 + (idx >> 6)] = W2[idx];
    }
    __syncthreads();

    if (bA >= batch) return;

    const int  j     = lane;
    const bool half0 = (lane < 32);

    // Split-form W1 rows: wq*yi_q + wr*yi_r == w1_0j*yi0 + w1_1j*yi1 per lane.
    const float wqv = half0 ? W1[j] : W1[64 + j];
    const float wrv = half0 ? W1[64 + j] : W1[j];
    const float b1v = B1[j], b2v = B2[j];
    const float w3_0 = W3[2 * j], w3_1 = W3[2 * j + 1];
    const float b3l0 = (lane == 0) ? B3[0] : 0.0f;   // folded into lane-0 terms
    const float b3l1 = (lane == 0) ? B3[1] : 0.0f;

    // Pin lane j's W2 column in registers via volatile one-time LDS reads
    // (exactly-once semantics: cannot be sunk/remat'd; R12 verified VGPR=88
    // i.e. resident). Padded stride 66 avoids the one-time 32-way conflicts.
    f32x2 w2p[32];
    {
        volatile const float* col = sW2T + j * 66;
        #pragma unroll
        for (int i = 0; i < 32; ++i) {
            w2p[i].x = col[2 * i];
            w2p[i].y = col[2 * i + 1];
        }
    }

    // bpermute lane-select addresses (bytes = lane*4).
    const int a1  = ((lane ^ 1)  << 2);
    const int a2  = ((lane ^ 2)  << 2);
    const int a4  = ((lane ^ 4)  << 2);
    const int a8  = ((lane ^ 8)  << 2);
    const int a16 = ((lane ^ 16) << 2);
    const int a32 = ((lane ^ 32) << 2);

    // Split-form state: y_q = (lane<32 ? y0 : y1), y_r the swap.
    float yA0 = y0_in[2 * bA], yA1 = y0_in[2 * bA + 1];
    float yB0 = y0_in[2 * bB], yB1 = y0_in[2 * bB + 1];
    float yAq = half0 ? yA0 : yA1, yAr = half0 ? yA1 : yA0;
    float yBq = half0 ? yB0 : yB1, yBr = half0 ? yB1 : yB0;

    float* outA = out + (size_t)bA * (2 * (N_STEPS + 1));
    float* outB = out + (size_t)bB * (2 * (N_STEPS + 1));
    if (lane == 0) {
        reinterpret_cast<float2*>(outA)[0] = make_float2(yAq, yAr);
        reinterpret_cast<float2*>(outB)[0] = make_float2(yBq, yBr);
    }

    float* hlA = hl_all[wib][0];
    float* hlB = hl_all[wib][1];
    const f32x4* hpA4 = (const f32x4*)hlA;
    const f32x4* hpB4 = (const f32x4*)hlB;

    const float chdt = 0.5f * DT_F, cdt = DT_F, cdt6 = DT_F / 6.0f;

    // Two-sample eval: doubles in-wave ILP over the serial DS/tanh chains
    // while sharing the 64 weight registers.
    auto net2 = [&](float iAq, float iAr, float iBq, float iBr,
                    float& kAq, float& kAr, float& kBq, float& kBr) {
        float hA = fast_tanh(fmaf(wqv, iAq, fmaf(wrv, iAr, b1v)));
        float hB = fast_tanh(fmaf(wqv, iBq, fmaf(wrv, iBr, b1v)));
        hlA[lane] = hA;
        hlB[lane] = hB;
        __builtin_amdgcn_wave_barrier();   // writes before reads (in-wave order)

        f32x2 aA0 = (f32x2){b2v, 0.0f}, aA1 = (f32x2){0.0f, 0.0f};
        f32x2 aA2 = (f32x2){0.0f, 0.0f}, aA3 = (f32x2){0.0f, 0.0f};
        f32x2 aB0 = (f32x2){b2v, 0.0f}, aB1 = (f32x2){0.0f, 0.0f};
        f32x2 aB2 = (f32x2){0.0f, 0.0f}, aB3 = (f32x2){0.0f, 0.0f};
        #pragma unroll
        for (int c = 0; c < 16; c += 2) {
            f32x4 hA0 = hpA4[c], hA1 = hpA4[c + 1];   // uniform-addr broadcasts
            f32x4 hB0 = hpB4[c], hB1 = hpB4[c + 1];
            aA0 = __builtin_elementwise_fma(lo2(hA0), w2p[2 * c + 0], aA0);
            aA1 = __builtin_elementwise_fma(hi2(hA0), w2p[2 * c + 1], aA1);
            aA2 = __builtin_elementwise_fma(lo2(hA1), w2p[2 * c + 2], aA2);
            aA3 = __builtin_elementwise_fma(hi2(hA1), w2p[2 * c + 3], aA3);
            aB0 = __builtin_elementwise_fma(lo2(hB0), w2p[2 * c + 0], aB0);
            aB1 = __builtin_elementwise_fma(hi2(hB0), w2p[2 * c + 1], aB1);
            aB2 = __builtin_elementwise_fma(lo2(hB1), w2p[2 * c + 2], aB2);
            aB3 = __builtin_elementwise_fma(hi2(hB1), w2p[2 * c + 3], aB3);
        }
        __builtin_amdgcn_wave_barrier();   // reads done before next eval's write

        f32x2 sA = (aA0 + aA1) + (aA2 + aA3);
        f32x2 sB = (aB0 + aB1) + (aB2 + aB3);
        float h2A = fast_tanh(sA.x + sA.y);
        float h2B = fast_tanh(sB.x + sB.y);
        float pA0 = fmaf(h2A, w3_0, b3l0), pA1 = fmaf(h2A, w3_1, b3l1);
        float pB0 = fmaf(h2B, w3_0, b3l0), pB1 = fmaf(h2B, w3_1, b3l1);
        kreduce(pA0, pA1, half0, a1, a2, a4, a8, a16, a32, kAq, kAr);
        kreduce(pB0, pB1, half0, a1, a2, a4, a8, a16, a32, kBq, kBr);
    };

    for (int t = 1; t <= N_STEPS; ++t) {
        float k1Aq, k1Ar, k1Bq, k1Br, k2Aq, k2Ar, k2Bq, k2Br;
        float k3Aq, k3Ar, k3Bq, k3Br, k4Aq, k4Ar, k4Bq, k4Br;
        net2(yAq, yAr, yBq, yBr, k1Aq, k1Ar, k1Bq, k1Br);
        net2(fmaf(chdt, k1Aq, yAq), fmaf(chdt, k1Ar, yAr),
             fmaf(chdt, k1Bq, yBq), fmaf(chdt, k1Br, yBr),
             k2Aq, k2Ar, k2Bq, k2Br);
        net2(fmaf(chdt, k2Aq, yAq), fmaf(chdt, k2Ar, yAr),
             fmaf(chdt, k2Bq, yBq), fmaf(chdt, k2Br, yBr),
             k3Aq, k3Ar, k3Bq, k3Br);
        net2(fmaf(cdt, k3Aq, yAq), fmaf(cdt, k3Ar, yAr),
             fmaf(cdt, k3Bq, yBq), fmaf(cdt, k3Br, yBr),
             k4Aq, k4Ar, k4Bq, k4Br);
        yAq = fmaf(cdt6, (k1Aq + k4Aq) + 2.0f * (k2Aq + k3Aq), yAq);
        yAr = fmaf(cdt6, (k1Ar + k4Ar) + 2.0f * (k2Ar + k3Ar), yAr);
        yBq = fmaf(cdt6, (k1Bq + k4Bq) + 2.0f * (k2Bq + k3Bq), yBq);
        yBr = fmaf(cdt6, (k1Br + k4Br) + 2.0f * (k2Br + k3Br), yBr);
        if (lane == 0) {
            reinterpret_cast<float2*>(outA)[t] = make_float2(yAq, yAr);
            reinterpret_cast<float2*>(outB)[t] = make_float2(yBq, yBr);
        }
    }
}

extern "C" void kernel_launch(void* const* d_in, const int* in_sizes, int n_in,
                              void* d_out, int out_size, void* d_ws, size_t ws_size,
                              hipStream_t stream) {
    const float* y0 = (const float*)d_in[0];
    const float* W1 = (const float*)d_in[1];
    const float* B1 = (const float*)d_in[2];
    const float* W2 = (const float*)d_in[3];
    const float* B2 = (const float*)d_in[4];
    const float* W3 = (const float*)d_in[5];
    const float* B3 = (const float*)d_in[6];
    float* out = (float*)d_out;

    const int batch = in_sizes[0] / 2;
    const int blocks = (batch + 7) / 8;   // 4 waves/block, 2 samples/wave

    node_rk4_kernel<<<blocks, 256, 0, stream>>>(y0, W1, B1, W2, B2, W3, B3, out, batch);
}